// Round 19
// baseline (8422.608 us; speedup 1.0000x reference)
//
#include <hip/hip_runtime.h>

#define NB 256      // batch
#define TT 1000     // total timesteps
#define HD 128      // hidden
#define NG 512      // 4*H, PyTorch gate order i,f,g,o

#define WGA __attribute__((amdgpu_flat_work_group_size(512,512), amdgpu_waves_per_eu(2,2)))
#define WGF __attribute__((amdgpu_flat_work_group_size(1024,1024), amdgpu_waves_per_eu(4,4)))

typedef __attribute__((ext_vector_type(8))) short s8v;   // 8 bf16 (MFMA A/B)
typedef __attribute__((ext_vector_type(4))) float f4v;   // MFMA C/D

__device__ __forceinline__ unsigned short bf16rne(float v) {
    unsigned u = __float_as_uint(v);
    unsigned r = u + 0x7FFF + ((u >> 16) & 1);
    return (unsigned short)(r >> 16);
}
__device__ __forceinline__ float bf16tof(unsigned short h) {
    return __uint_as_float(((unsigned)h) << 16);
}
__device__ __forceinline__ float sigf(float x) { return 1.f / (1.f + __expf(-x)); }
__device__ __forceinline__ float tanhfast(float x) {
    float e = __expf(-2.f * x);
    return 2.f / (1.f + e) - 1.f;
}

// r10's 128-element fp32 dot, software-pipelined with sched_barrier(0).
#define DOT128(h4, wv, A0, A1, A2, A3)                                        \
    {                                                                          \
        float4 c0=(h4)[0], c1=(h4)[1], c2=(h4)[2], c3=(h4)[3];                 \
        _Pragma("unroll")                                                      \
        for (int g = 0; g < 8; ++g) {                                          \
            float4 n0,n1,n2,n3;                                                \
            if (g < 7) { n0=(h4)[4*g+4]; n1=(h4)[4*g+5];                       \
                         n2=(h4)[4*g+6]; n3=(h4)[4*g+7]; }                     \
            A0 = fmaf(c0.x, wv[4*g+0].x, A0); A1 = fmaf(c0.y, wv[4*g+0].y, A1);\
            A2 = fmaf(c0.z, wv[4*g+0].z, A2); A3 = fmaf(c0.w, wv[4*g+0].w, A3);\
            A0 = fmaf(c1.x, wv[4*g+1].x, A0); A1 = fmaf(c1.y, wv[4*g+1].y, A1);\
            A2 = fmaf(c1.z, wv[4*g+1].z, A2); A3 = fmaf(c1.w, wv[4*g+1].w, A3);\
            A0 = fmaf(c2.x, wv[4*g+2].x, A0); A1 = fmaf(c2.y, wv[4*g+2].y, A1);\
            A2 = fmaf(c2.z, wv[4*g+2].z, A2); A3 = fmaf(c2.w, wv[4*g+2].w, A3);\
            A0 = fmaf(c3.x, wv[4*g+3].x, A0); A1 = fmaf(c3.y, wv[4*g+3].y, A1);\
            A2 = fmaf(c3.z, wv[4*g+3].z, A2); A3 = fmaf(c3.w, wv[4*g+3].w, A3);\
            __builtin_amdgcn_sched_barrier(0);                                 \
            if (g < 7) { c0=n0; c1=n1; c2=n2; c3=n3; }                         \
        }                                                                      \
    }

// ---------------- Fused recurrence: threads 0-511 = layer0(chunk n+1),
// threads 512-1023 = layer1(chunk n). Independent data; identical step
// structure -> shared barriers couple steps 1:1. Either half can idle (len=0).
__global__ WGF
void lstm_fused(const float* __restrict__ x,
                const float* __restrict__ Wih0, const float* __restrict__ Whh0,
                const float* __restrict__ bih0, const float* __restrict__ bhh0,
                float* __restrict__ h1out,
                float* __restrict__ hs1, float* __restrict__ cs1,
                int t0_1, int len1,
                const float* __restrict__ xg1c, const float* __restrict__ Whh1,
                float* __restrict__ h2out,
                float* __restrict__ hs2, float* __restrict__ cs2,
                int t0_3, int len3)
{
    __shared__ __align__(16) float h_lds1[HD];
    __shared__ float gbuf1[NG];
    __shared__ float x_lds[3 * TT];            // 12 KB
    __shared__ __align__(16) float h_lds3[HD];
    __shared__ float gbuf3[NG];
    const int tid = threadIdx.x;
    const int b = blockIdx.x;
    const bool isK1 = tid < 512;               // wave-uniform
    const int j = tid & 511;
    const int lenMax = (len1 > len3) ? len1 : len3;
    const int myLen = isK1 ? len1 : len3;

    float4 wv[HD/4];
    float wx0=0.f, wx1=0.f, wx2=0.f, bias=0.f;
    float c = 0.f, hcur = 0.f, xg_cur = 0.f;

    if (isK1) {
        if (len1 > 0) {
            const float4* wr = (const float4*)(Whh0 + (size_t)j * HD);
            #pragma unroll
            for (int q = 0; q < HD/4; ++q) wv[q] = wr[q];
            wx0 = Wih0[j*3+0]; wx1 = Wih0[j*3+1]; wx2 = Wih0[j*3+2];
            bias = bih0[j] + bhh0[j];
            for (int idx = j; idx < 3*len1; idx += 512)
                x_lds[idx] = x[((size_t)b*TT + t0_1)*3 + idx];
            if (j < HD) {
                if (t0_1 != 0) { hcur = hs1[b*HD+j]; c = cs1[b*HD+j]; }
                h_lds1[j] = hcur;
            }
        }
    } else {
        if (len3 > 0) {
            const float4* wr = (const float4*)(Whh1 + (size_t)j * HD);
            #pragma unroll
            for (int q = 0; q < HD/4; ++q) wv[q] = wr[q];
            if (j < HD) {
                if (t0_3 != 0) { hcur = hs2[b*HD+j]; c = cs2[b*HD+j]; }
                h_lds3[j] = hcur;
            }
            xg_cur = xg1c[((size_t)b*len3 + 0)*NG + j];
        }
    }
    __syncthreads();

    const int gtype = j >> 7;
    for (int i = 0; i < lenMax; ++i) {
        const bool doit = (i < myLen);
        float xg_nxt = 0.f;
        if (doit) {
            if (!isK1 && i+1 < len3)
                xg_nxt = xg1c[((size_t)b*len3 + i+1)*NG + j];   // prefetch
            float a0=0.f,a1=0.f,a2=0.f,a3=0.f;
            const float4* h4 = (const float4*)(isK1 ? h_lds1 : h_lds3);
            DOT128(h4, wv, a0, a1, a2, a3);
            float acc = (a0+a1)+(a2+a3);
            if (isK1) {
                acc += bias;
                acc = fmaf(wx0, x_lds[3*i+0], acc);
                acc = fmaf(wx1, x_lds[3*i+1], acc);
                acc = fmaf(wx2, x_lds[3*i+2], acc);
            } else {
                acc += xg_cur;      // K2 folded biases in
            }
            float act = (gtype == 2) ? tanhfast(acc) : sigf(acc);
            (isK1 ? gbuf1 : gbuf3)[j] = act;
        }
        __syncthreads();                 // barrier A (all 1024 threads)
        if (doit && j < HD) {
            float* gb = isK1 ? gbuf1 : gbuf3;
            float ig = gb[j], fg = gb[HD+j], gg = gb[2*HD+j], og = gb[3*HD+j];
            c = fmaf(fg, c, ig*gg);
            hcur = og * tanhfast(c);
            (isK1 ? h_lds1 : h_lds3)[j] = hcur;
            if (isK1) h1out[((size_t)b*len1 + i)*HD + j] = hcur;
            else      h2out[((size_t)b*len3 + i)*HD + j] = hcur;
        }
        __syncthreads();                 // barrier B
        xg_cur = xg_nxt;
    }
    if (j < HD) {
        if (isK1) { if (len1 > 0) { hs1[b*HD+j] = hcur; cs1[b*HD+j] = c; } }
        else      { if (len3 > 0) { hs2[b*HD+j] = hcur; cs2[b*HD+j] = c; } }
    }
}

// ---------------- K2: xg1 = h1 @ W_ih_l1^T + biases — MFMA GEMM (r18-proven, ~40us) ----------------
__global__ WGA
void xgate_gemm(const float* __restrict__ h1c,
                const float* __restrict__ Wih1,
                const float* __restrict__ bih1, const float* __restrict__ bhh1,
                float* __restrict__ xg1c, int len)
{
    __shared__ float bsum[NG];
    const int j = threadIdx.x;
    const int b = blockIdx.x;
    const int wv = j >> 6, lane = j & 63, lq = lane >> 4, lm = lane & 15;

    s8v Ah[4][4], Al[4][4];
    {
        #pragma unroll
        for (int t = 0; t < 4; ++t) {
            const int m = 64*wv + 16*t + lm;
            const float* wrow = Wih1 + (size_t)m * HD;
            #pragma unroll
            for (int kc = 0; kc < 4; ++kc) {
                const int k0 = 32*kc + 4*lq;
                float4 va = *(const float4*)(wrow + k0);
                float4 vb = *(const float4*)(wrow + k0 + 16);
                float vs[8] = {va.x,va.y,va.z,va.w,vb.x,vb.y,vb.z,vb.w};
                s8v ah, al;
                #pragma unroll
                for (int e = 0; e < 8; ++e) {
                    unsigned short hb = bf16rne(vs[e]);
                    float lo = vs[e] - bf16tof(hb);
                    ah[e] = (short)hb; al[e] = (short)bf16rne(lo);
                }
                Ah[t][kc] = ah; Al[t][kc] = al;
            }
        }
    }
    bsum[j] = bih1[j] + bhh1[j];
    __syncthreads();

    for (int ts = 0; ts < len; ts += 16) {
        const int trow = (ts + lm < len) ? (ts + lm) : (len - 1);
        const float* hrow = h1c + ((size_t)b*len + trow)*HD;
        s8v Bh[4], Bl[4];
        #pragma unroll
        for (int kc = 0; kc < 4; ++kc) {
            const int k0 = 32*kc + 4*lq;
            float4 va = *(const float4*)(hrow + k0);
            float4 vb = *(const float4*)(hrow + k0 + 16);
            float vs[8] = {va.x,va.y,va.z,va.w,vb.x,vb.y,vb.z,vb.w};
            s8v hh, hl;
            #pragma unroll
            for (int e = 0; e < 8; ++e) {
                unsigned short hb = bf16rne(vs[e]);
                float lo = vs[e] - bf16tof(hb);
                hh[e] = (short)hb; hl[e] = (short)bf16rne(lo);
            }
            Bh[kc] = hh; Bl[kc] = hl;
        }
        f4v zz = {0.f,0.f,0.f,0.f};
        f4v accA[4] = {zz,zz,zz,zz}, accB[4] = {zz,zz,zz,zz};
        #pragma unroll
        for (int kc = 0; kc < 4; ++kc) {
            #pragma unroll
            for (int t = 0; t < 4; ++t)
                accA[t] = __builtin_amdgcn_mfma_f32_16x16x32_bf16(Ah[t][kc], Bh[kc], accA[t], 0,0,0);
        }
        #pragma unroll
        for (int kc = 0; kc < 4; ++kc) {
            #pragma unroll
            for (int t = 0; t < 4; ++t)
                accB[t] = __builtin_amdgcn_mfma_f32_16x16x32_bf16(Al[t][kc], Bh[kc], accB[t], 0,0,0);
        }
        #pragma unroll
        for (int kc = 0; kc < 4; ++kc) {
            #pragma unroll
            for (int t = 0; t < 4; ++t)
                accB[t] = __builtin_amdgcn_mfma_f32_16x16x32_bf16(Ah[t][kc], Bl[kc], accB[t], 0,0,0);
        }
        if (ts + lm < len) {
            float* xrow = xg1c + ((size_t)b*len + ts + lm)*NG;
            #pragma unroll
            for (int t = 0; t < 4; ++t) {
                const int r0 = 64*wv + 16*t + 4*lq;
                float4 o;
                o.x = accA[t][0]+accB[t][0] + bsum[r0+0];
                o.y = accA[t][1]+accB[t][1] + bsum[r0+1];
                o.z = accA[t][2]+accB[t][2] + bsum[r0+2];
                o.w = accA[t][3]+accB[t][3] + bsum[r0+3];
                *(float4*)&xrow[r0] = o;
            }
        }
    }
}

// ---------------- K4: y = h2 @ fcw^T + fcb — wave-per-row, fp32 ----------------
__global__ __launch_bounds__(512, 1)
void fc_head(const float* __restrict__ h2c,
             const float* __restrict__ fcw, const float* __restrict__ fcb,
             float* __restrict__ y, int t0, int len)
{
    const int b = blockIdx.x;
    const int wid = threadIdx.x >> 6;
    const int lane = threadIdx.x & 63;
    const float f0a = fcw[0*HD+lane], f0b = fcw[0*HD+64+lane];
    const float f1a = fcw[1*HD+lane], f1b = fcw[1*HD+64+lane];
    const float f2a = fcw[2*HD+lane], f2b = fcw[2*HD+64+lane];
    const float fb = (lane < 3) ? fcb[lane] : 0.f;
    for (int tc = wid; tc < len; tc += 8) {
        const float* hp = h2c + ((size_t)b*len + tc)*HD;
        float ha = hp[lane], hb = hp[64+lane];
        float y0 = ha*f0a + hb*f0b;
        float y1 = ha*f1a + hb*f1b;
        float y2 = ha*f2a + hb*f2b;
        #pragma unroll
        for (int m = 1; m < 64; m <<= 1) {
            y0 += __shfl_xor(y0, m);
            y1 += __shfl_xor(y1, m);
            y2 += __shfl_xor(y2, m);
        }
        if (lane < 3) {
            float yv = (lane==0) ? y0 : (lane==1) ? y1 : y2;
            y[((size_t)b*TT + (t0+tc))*3 + lane] = yv + fb;
        }
    }
}

extern "C" void kernel_launch(void* const* d_in, const int* in_sizes, int n_in,
                              void* d_out, int out_size, void* d_ws, size_t ws_size,
                              hipStream_t stream)
{
    const float* x    = (const float*)d_in[0];
    const float* Wih0 = (const float*)d_in[1];
    const float* Whh0 = (const float*)d_in[2];
    const float* bih0 = (const float*)d_in[3];
    const float* bhh0 = (const float*)d_in[4];
    const float* Wih1 = (const float*)d_in[5];
    const float* Whh1 = (const float*)d_in[6];
    const float* bih1 = (const float*)d_in[7];
    const float* bhh1 = (const float*)d_in[8];
    const float* fcw  = (const float*)d_in[9];
    const float* fcb  = (const float*)d_in[10];
    float* y = (float*)d_out;

    // ws layout: h1c x2 (dbuf) + xg1c + h2c + 4 state bufs (ws-derived -> deterministic)
    const size_t stateBytes = 4ull * NB * HD * sizeof(float);                 // 512 KB
    const size_t perT = (size_t)NB * (2*HD + NG + HD) * sizeof(float);        // 917504 B
    long tcl = (ws_size > stateBytes) ? (long)((ws_size - stateBytes) / perT) : 1;
    if (tcl > TT) tcl = TT;
    if (tcl < 1)  tcl = 1;
    const int NC = (int)((TT + tcl - 1) / tcl);       // number of chunks
    const int Tc = (TT + NC - 1) / NC;                 // even-ish chunks

    float* h1c0 = (float*)d_ws;
    float* h1c1 = h1c0 + (size_t)NB * Tc * HD;
    float* xg1c = h1c1 + (size_t)NB * Tc * HD;
    float* h2c  = xg1c + (size_t)NB * Tc * NG;
    float* hs1  = h2c  + (size_t)NB * Tc * HD;
    float* cs1  = hs1 + NB*HD;
    float* hs2  = cs1 + NB*HD;
    float* cs2  = hs2 + NB*HD;
    float* h1b[2] = { h1c0, h1c1 };

    // chunk n: t0 = n*Tc, len = min(Tc, TT - t0)
    #define T0(n)  ((n) * Tc)
    #define LEN(n) ((TT - T0(n) < Tc) ? (TT - T0(n)) : Tc)

    // K1(0) alone (K3 half idle)
    lstm_fused<<<dim3(NB), dim3(1024), 0, stream>>>(
        x, Wih0, Whh0, bih0, bhh0, h1b[0], hs1, cs1, T0(0), LEN(0),
        xg1c, Whh1, h2c, hs2, cs2, 0, 0);
    xgate_gemm<<<dim3(NB), dim3(512), 0, stream>>>(
        h1b[0], Wih1, bih1, bhh1, xg1c, LEN(0));

    for (int n = 0; n + 1 < NC; ++n) {
        // K1(n+1) || K3(n)
        lstm_fused<<<dim3(NB), dim3(1024), 0, stream>>>(
            x, Wih0, Whh0, bih0, bhh0, h1b[(n+1)&1], hs1, cs1, T0(n+1), LEN(n+1),
            xg1c, Whh1, h2c, hs2, cs2, T0(n), LEN(n));
        fc_head<<<dim3(NB), dim3(512), 0, stream>>>(
            h2c, fcw, fcb, y, T0(n), LEN(n));
        xgate_gemm<<<dim3(NB), dim3(512), 0, stream>>>(
            h1b[(n+1)&1], Wih1, bih1, bhh1, xg1c, LEN(n+1));
    }

    // K3(NC-1) alone (K1 half idle)
    lstm_fused<<<dim3(NB), dim3(1024), 0, stream>>>(
        x, Wih0, Whh0, bih0, bhh0, h1b[0], hs1, cs1, 0, 0,
        xg1c, Whh1, h2c, hs2, cs2, T0(NC-1), LEN(NC-1));
    fc_head<<<dim3(NB), dim3(512), 0, stream>>>(
        h2c, fcw, fcb, y, T0(NC-1), LEN(NC-1));

    #undef T0
    #undef LEN
}

// Round 20
// 1951.705 us; speedup vs baseline: 4.3155x; 4.3155x over previous
//
#include <hip/hip_runtime.h>

#define NB 256      // batch
#define TT 1000     // total timesteps
#define HD 128      // hidden
#define NG 512      // 4*H, PyTorch gate order i,f,g,o

// 8 waves/block at 1 block/CU = exactly 2 waves/EU (256-VGPR budget — r19 lesson:
// NEVER go to 1024 threads with register-resident weights).
#define WGA __attribute__((amdgpu_flat_work_group_size(512,512), amdgpu_waves_per_eu(2,2)))

typedef __attribute__((ext_vector_type(8))) short s8v;   // 8 bf16 (MFMA A/B)
typedef __attribute__((ext_vector_type(4))) float f4v;   // MFMA C/D

__device__ __forceinline__ unsigned short bf16rne(float v) {
    unsigned u = __float_as_uint(v);
    unsigned r = u + 0x7FFF + ((u >> 16) & 1);
    return (unsigned short)(r >> 16);
}
__device__ __forceinline__ float bf16tof(unsigned short h) {
    return __uint_as_float(((unsigned)h) << 16);
}
__device__ __forceinline__ float sigf(float x) { return 1.f / (1.f + __expf(-x)); }
__device__ __forceinline__ float tanhfast(float x) {
    float e = __expf(-2.f * x);
    return 2.f / (1.f + e) - 1.f;
}

// Packed fp32 FMA: one VOP3P inst = 2 exact fp32 FMAs (gfx90a+).
// acc, h, w are float2 in aligned VGPR pairs (all come from b128 loads).
#define PKFMA(acc, h, w) \
    asm("v_pk_fma_f32 %0, %1, %2, %0" : "+v"(acc) : "v"(h), "v"(w))

__device__ __forceinline__ float2 lo2(float4 v) { return make_float2(v.x, v.y); }
__device__ __forceinline__ float2 hi2(float4 v) { return make_float2(v.z, v.w); }

// 128-MAC dot as 64 v_pk_fma_f32, 4 float2 accumulators, grouped loads with
// sched_barrier(0) (r10: grouping prevents whole-loop load hoisting, +10%).
#define DOT128P(h4, wv, P0, P1, P2, P3)                                        \
    {                                                                          \
        _Pragma("unroll")                                                      \
        for (int g = 0; g < 8; ++g) {                                          \
            float4 c0=(h4)[4*g+0], c1=(h4)[4*g+1],                             \
                   c2=(h4)[4*g+2], c3=(h4)[4*g+3];                             \
            PKFMA(P0, lo2(c0), lo2(wv[4*g+0]));                                \
            PKFMA(P1, hi2(c0), hi2(wv[4*g+0]));                                \
            PKFMA(P2, lo2(c1), lo2(wv[4*g+1]));                                \
            PKFMA(P3, hi2(c1), hi2(wv[4*g+1]));                                \
            PKFMA(P0, lo2(c2), lo2(wv[4*g+2]));                                \
            PKFMA(P1, hi2(c2), hi2(wv[4*g+2]));                                \
            PKFMA(P2, lo2(c3), lo2(wv[4*g+3]));                                \
            PKFMA(P3, hi2(c3), hi2(wv[4*g+3]));                                \
            __builtin_amdgcn_sched_barrier(0);                                 \
        }                                                                      \
    }

// ---------------- K1: layer-0 recurrence (r18 structure, pk-fma dot) ----------------
__global__ WGA
void lstm_layer0(const float* __restrict__ x,
                 const float* __restrict__ Wih, const float* __restrict__ Whh,
                 const float* __restrict__ bih, const float* __restrict__ bhh,
                 float* __restrict__ h1c,
                 float* __restrict__ hstate, float* __restrict__ cstate,
                 int t0, int len)
{
    __shared__ __align__(16) float h_lds[HD];
    __shared__ float gbuf[NG];
    __shared__ float x_lds[3 * TT];   // 12 KB
    const int j = threadIdx.x;
    const int b = blockIdx.x;

    float4 wv[HD/4];   // W_hh row j
    {
        const float4* wr = (const float4*)(Whh + (size_t)j * HD);
        #pragma unroll
        for (int q = 0; q < HD/4; ++q) wv[q] = wr[q];
    }
    const float wx0 = Wih[j*3+0], wx1 = Wih[j*3+1], wx2 = Wih[j*3+2];
    const float bias = bih[j] + bhh[j];

    for (int idx = j; idx < 3*len; idx += 512)
        x_lds[idx] = x[((size_t)b*TT + t0)*3 + idx];

    float c = 0.f, hcur = 0.f;
    if (j < HD) {
        if (t0 != 0) { hcur = hstate[b*HD+j]; c = cstate[b*HD+j]; }
        h_lds[j] = hcur;
    }
    __syncthreads();

    const int gtype = j >> 7;   // 0:i 1:f 2:g 3:o — wave-uniform
    for (int tc = 0; tc < len; ++tc) {
        float2 p0 = {0.f,0.f}, p1 = {0.f,0.f}, p2 = {0.f,0.f}, p3 = {0.f,0.f};
        const float4* h4 = (const float4*)h_lds;   // uniform addr -> LDS broadcast
        DOT128P(h4, wv, p0, p1, p2, p3);
        float acc = bias + ((p0.x+p0.y)+(p1.x+p1.y)) + ((p2.x+p2.y)+(p3.x+p3.y));
        acc = fmaf(wx0, x_lds[3*tc+0], acc);
        acc = fmaf(wx1, x_lds[3*tc+1], acc);
        acc = fmaf(wx2, x_lds[3*tc+2], acc);
        float act = (gtype == 2) ? tanhfast(acc) : sigf(acc);
        gbuf[j] = act;
        __syncthreads();                 // barrier A: gates visible
        if (j < HD) {
            float ig = gbuf[j], fg = gbuf[HD+j], gg = gbuf[2*HD+j], og = gbuf[3*HD+j];
            c = fmaf(fg, c, ig*gg);
            hcur = og * tanhfast(c);
            h_lds[j] = hcur;
            h1c[((size_t)b*len + tc)*HD + j] = hcur;
        }
        __syncthreads();                 // barrier B: new h visible
    }
    if (j < HD) { hstate[b*HD+j] = hcur; cstate[b*HD+j] = c; }
}

// ---------------- K2: xg1 = h1 @ W_ih_l1^T + biases — MFMA GEMM (r18-proven, ~40us) ----------------
__global__ WGA
void xgate_gemm(const float* __restrict__ h1c,
                const float* __restrict__ Wih1,
                const float* __restrict__ bih1, const float* __restrict__ bhh1,
                float* __restrict__ xg1c, int len)
{
    __shared__ float bsum[NG];
    const int j = threadIdx.x;
    const int b = blockIdx.x;
    const int wv = j >> 6, lane = j & 63, lq = lane >> 4, lm = lane & 15;

    s8v Ah[4][4], Al[4][4];
    {
        #pragma unroll
        for (int t = 0; t < 4; ++t) {
            const int m = 64*wv + 16*t + lm;
            const float* wrow = Wih1 + (size_t)m * HD;
            #pragma unroll
            for (int kc = 0; kc < 4; ++kc) {
                const int k0 = 32*kc + 4*lq;
                float4 va = *(const float4*)(wrow + k0);
                float4 vb = *(const float4*)(wrow + k0 + 16);
                float vs[8] = {va.x,va.y,va.z,va.w,vb.x,vb.y,vb.z,vb.w};
                s8v ah, al;
                #pragma unroll
                for (int e = 0; e < 8; ++e) {
                    unsigned short hb = bf16rne(vs[e]);
                    float lo = vs[e] - bf16tof(hb);
                    ah[e] = (short)hb; al[e] = (short)bf16rne(lo);
                }
                Ah[t][kc] = ah; Al[t][kc] = al;
            }
        }
    }
    bsum[j] = bih1[j] + bhh1[j];
    __syncthreads();

    for (int ts = 0; ts < len; ts += 16) {
        const int trow = (ts + lm < len) ? (ts + lm) : (len - 1);
        const float* hrow = h1c + ((size_t)b*len + trow)*HD;
        s8v Bh[4], Bl[4];
        #pragma unroll
        for (int kc = 0; kc < 4; ++kc) {
            const int k0 = 32*kc + 4*lq;
            float4 va = *(const float4*)(hrow + k0);
            float4 vb = *(const float4*)(hrow + k0 + 16);
            float vs[8] = {va.x,va.y,va.z,va.w,vb.x,vb.y,vb.z,vb.w};
            s8v hh, hl;
            #pragma unroll
            for (int e = 0; e < 8; ++e) {
                unsigned short hb = bf16rne(vs[e]);
                float lo = vs[e] - bf16tof(hb);
                hh[e] = (short)hb; hl[e] = (short)bf16rne(lo);
            }
            Bh[kc] = hh; Bl[kc] = hl;
        }
        f4v zz = {0.f,0.f,0.f,0.f};
        f4v accA[4] = {zz,zz,zz,zz}, accB[4] = {zz,zz,zz,zz};
        #pragma unroll
        for (int kc = 0; kc < 4; ++kc) {
            #pragma unroll
            for (int t = 0; t < 4; ++t)
                accA[t] = __builtin_amdgcn_mfma_f32_16x16x32_bf16(Ah[t][kc], Bh[kc], accA[t], 0,0,0);
        }
        #pragma unroll
        for (int kc = 0; kc < 4; ++kc) {
            #pragma unroll
            for (int t = 0; t < 4; ++t)
                accB[t] = __builtin_amdgcn_mfma_f32_16x16x32_bf16(Al[t][kc], Bh[kc], accB[t], 0,0,0);
        }
        #pragma unroll
        for (int kc = 0; kc < 4; ++kc) {
            #pragma unroll
            for (int t = 0; t < 4; ++t)
                accB[t] = __builtin_amdgcn_mfma_f32_16x16x32_bf16(Ah[t][kc], Bl[kc], accB[t], 0,0,0);
        }
        if (ts + lm < len) {
            float* xrow = xg1c + ((size_t)b*len + ts + lm)*NG;
            #pragma unroll
            for (int t = 0; t < 4; ++t) {
                const int r0 = 64*wv + 16*t + 4*lq;
                float4 o;
                o.x = accA[t][0]+accB[t][0] + bsum[r0+0];
                o.y = accA[t][1]+accB[t][1] + bsum[r0+1];
                o.z = accA[t][2]+accB[t][2] + bsum[r0+2];
                o.w = accA[t][3]+accB[t][3] + bsum[r0+3];
                *(float4*)&xrow[r0] = o;
            }
        }
    }
}

// ---------------- K3: layer-1 recurrence (r18 structure, pk-fma dot) ----------------
__global__ WGA
void lstm_layer1(const float* __restrict__ xg1c,
                 const float* __restrict__ Whh1,
                 float* __restrict__ h2c,
                 float* __restrict__ hstate, float* __restrict__ cstate,
                 int t0, int len)
{
    __shared__ __align__(16) float h_lds[HD];
    __shared__ float gbuf[NG];
    const int j = threadIdx.x;
    const int b = blockIdx.x;
    float4 wv[HD/4];   // W_hh_l1 row j
    {
        const float4* wr = (const float4*)(Whh1 + (size_t)j * HD);
        #pragma unroll
        for (int q = 0; q < HD/4; ++q) wv[q] = wr[q];
    }
    float c = 0.f, hcur = 0.f;
    if (j < HD) {
        if (t0 != 0) { hcur = hstate[b*HD+j]; c = cstate[b*HD+j]; }
        h_lds[j] = hcur;
    }
    __syncthreads();
    const int gtype = j >> 7;
    float xg_cur = xg1c[((size_t)b*len + 0)*NG + j];
    for (int tc = 0; tc < len; ++tc) {
        float xg_nxt = 0.f;
        if (tc+1 < len) xg_nxt = xg1c[((size_t)b*len + tc+1)*NG + j]; // prefetch
        float2 p0 = {0.f,0.f}, p1 = {0.f,0.f}, p2 = {0.f,0.f}, p3 = {0.f,0.f};
        const float4* h4 = (const float4*)h_lds;
        DOT128P(h4, wv, p0, p1, p2, p3);
        float acc = xg_cur + ((p0.x+p0.y)+(p1.x+p1.y)) + ((p2.x+p2.y)+(p3.x+p3.y));
        float act = (gtype == 2) ? tanhfast(acc) : sigf(acc);
        gbuf[j] = act;
        __syncthreads();                 // barrier A
        if (j < HD) {
            float ig = gbuf[j], fg = gbuf[HD+j], gg = gbuf[2*HD+j], og = gbuf[3*HD+j];
            c = fmaf(fg, c, ig*gg);
            hcur = og * tanhfast(c);
            h_lds[j] = hcur;
            h2c[((size_t)b*len + tc)*HD + j] = hcur;
        }
        __syncthreads();                 // barrier B
        xg_cur = xg_nxt;
    }
    if (j < HD) { hstate[b*HD+j] = hcur; cstate[b*HD+j] = c; }
}

// ---------------- K4: y = h2 @ fcw^T + fcb — wave-per-row, fp32 ----------------
__global__ __launch_bounds__(512, 1)
void fc_head(const float* __restrict__ h2c,
             const float* __restrict__ fcw, const float* __restrict__ fcb,
             float* __restrict__ y, int t0, int len)
{
    const int b = blockIdx.x;
    const int wid = threadIdx.x >> 6;
    const int lane = threadIdx.x & 63;
    const float f0a = fcw[0*HD+lane], f0b = fcw[0*HD+64+lane];
    const float f1a = fcw[1*HD+lane], f1b = fcw[1*HD+64+lane];
    const float f2a = fcw[2*HD+lane], f2b = fcw[2*HD+64+lane];
    const float fb = (lane < 3) ? fcb[lane] : 0.f;
    for (int tc = wid; tc < len; tc += 8) {
        const float* hp = h2c + ((size_t)b*len + tc)*HD;
        float ha = hp[lane], hb = hp[64+lane];
        float y0 = ha*f0a + hb*f0b;
        float y1 = ha*f1a + hb*f1b;
        float y2 = ha*f2a + hb*f2b;
        #pragma unroll
        for (int m = 1; m < 64; m <<= 1) {
            y0 += __shfl_xor(y0, m);
            y1 += __shfl_xor(y1, m);
            y2 += __shfl_xor(y2, m);
        }
        if (lane < 3) {
            float yv = (lane==0) ? y0 : (lane==1) ? y1 : y2;
            y[((size_t)b*TT + (t0+tc))*3 + lane] = yv + fb;
        }
    }
}

extern "C" void kernel_launch(void* const* d_in, const int* in_sizes, int n_in,
                              void* d_out, int out_size, void* d_ws, size_t ws_size,
                              hipStream_t stream)
{
    const float* x    = (const float*)d_in[0];
    const float* Wih0 = (const float*)d_in[1];
    const float* Whh0 = (const float*)d_in[2];
    const float* bih0 = (const float*)d_in[3];
    const float* bhh0 = (const float*)d_in[4];
    const float* Wih1 = (const float*)d_in[5];
    const float* Whh1 = (const float*)d_in[6];
    const float* bih1 = (const float*)d_in[7];
    const float* bhh1 = (const float*)d_in[8];
    const float* fcw  = (const float*)d_in[9];
    const float* fcb  = (const float*)d_in[10];
    float* y = (float*)d_out;

    // ws layout: h1 chunk + xg1 chunk + 4 state bufs (ws-derived -> deterministic)
    const size_t stateBytes = 4ull * NB * HD * sizeof(float);
    const size_t perT = (size_t)NB*HD*sizeof(float) + (size_t)NB*NG*sizeof(float);
    long tcl = (ws_size > stateBytes) ? (long)((ws_size - stateBytes) / perT) : 1;
    if (tcl > TT) tcl = TT;
    if (tcl < 1)  tcl = 1;
    const int Tc = (int)tcl;

    float* h1c  = (float*)d_ws;
    float* xg1c = h1c  + (size_t)NB * Tc * HD;
    float* hs1  = xg1c + (size_t)NB * Tc * NG;
    float* cs1  = hs1 + NB*HD;
    float* hs2  = cs1 + NB*HD;
    float* cs2  = hs2 + NB*HD;
    float* h2c  = h1c;   // h1c dead after K2 — reuse for h2

    for (int t0 = 0; t0 < TT; t0 += Tc) {
        const int len = (TT - t0 < Tc) ? (TT - t0) : Tc;
        lstm_layer0<<<dim3(NB), dim3(512), 0, stream>>>(
            x, Wih0, Whh0, bih0, bhh0, h1c, hs1, cs1, t0, len);
        xgate_gemm<<<dim3(NB), dim3(512), 0, stream>>>(
            h1c, Wih1, bih1, bhh1, xg1c, len);
        lstm_layer1<<<dim3(NB), dim3(512), 0, stream>>>(
            xg1c, Whh1, h2c, hs2, cs2, t0, len);
        fc_head<<<dim3(NB), dim3(512), 0, stream>>>(
            h2c, fcw, fcb, y, t0, len);
    }
}